// Round 7
// baseline (191.394 us; speedup 1.0000x reference)
//
#include <hip/hip_runtime.h>
#include <hip/hip_bf16.h>

// MaskedAttention: out = softmax(tril(q k^T)) v, q/k/v = x @ W{q,k,v}
// B=8 T=2048 D=1024 H=64, fp32 in/out, no 1/sqrt(H) scaling.
//
// Precision plan: q,k projections and QK^T use hi/lo bf16 splitting
// (3-MFMA "bf16x3") so logits are ~fp32-accurate; V/P plain bf16.

typedef __bf16 bf16x8 __attribute__((ext_vector_type(8)));
typedef float f32x4 __attribute__((ext_vector_type(4)));

#define MFMA16(a, b, c) __builtin_amdgcn_mfma_f32_16x16x32_bf16((a), (b), (c), 0, 0, 0)
#define SB0() __builtin_amdgcn_sched_barrier(0)

static constexpr int BB = 8;
static constexpr int TT = 2048;
static constexpr int DD = 1024;
static constexpr int HH = 64;
static constexpr int NROW = BB * TT;       // 16384
// WC slab: [4 colgroups][2 K-halves][320 rows = k8l*5+frag][16 cols][8 bf16]
// frag: 0=q_hi 1=q_lo 2=k_hi 3=k_lo 4=v_hi. 80KB per (cg,half) slice.
static constexpr int WSLICE = 320 * 128;   // bf16 elems per (cg,half) = 80KB

__device__ __forceinline__ float rmax16(float v) {
#pragma unroll
  for (int m = 1; m < 16; m <<= 1) v = fmaxf(v, __shfl_xor(v, m, 64));
  return v;
}
__device__ __forceinline__ float rsum16(float v) {
#pragma unroll
  for (int m = 1; m < 16; m <<= 1) v += __shfl_xor(v, m, 64);
  return v;
}

// ---------------------------------------------------------------- W prep ---
// W [1024][64] fp32 -> WC slab (see above). Linear in (row,col) so proj can
// stage it to LDS with pure linear global_load_lds DMA.
__global__ __launch_bounds__(256) void wprep_kernel(
    const float* __restrict__ Wq, const float* __restrict__ Wk,
    const float* __restrict__ Wv, __bf16* __restrict__ WC) {
  int tid = blockIdx.x * 256 + threadIdx.x;
  if (tid >= 64 * 128) return;
  int col = tid >> 7;
  int k8 = tid & 127;
  const int g = col >> 4, c = col & 15;
  const int h2 = k8 >> 6, k8l = k8 & 63;
  bf16x8 q_h, q_l, k_h, k_l, v_h;
#pragma unroll
  for (int j = 0; j < 8; ++j) {
    const int k = k8 * 8 + j;
    float qv = Wq[k * 64 + col];
    float kv = Wk[k * 64 + col];
    float vv = Wv[k * 64 + col];
    __bf16 qhi = (__bf16)qv;
    __bf16 khi = (__bf16)kv;
    q_h[j] = qhi;
    q_l[j] = (__bf16)(qv - (float)qhi);
    k_h[j] = khi;
    k_l[j] = (__bf16)(kv - (float)khi);
    v_h[j] = (__bf16)vv;
  }
  __bf16* base = WC + (size_t)(g * 2 + h2) * WSLICE + (size_t)(k8l * 5) * 128 + c * 8;
  *(bf16x8*)(base) = q_h;            // row k8l*5+0
  *(bf16x8*)(base + 128) = q_l;      // row k8l*5+1
  *(bf16x8*)(base + 256) = k_h;      // row k8l*5+2
  *(bf16x8*)(base + 384) = k_l;      // row k8l*5+3
  *(bf16x8*)(base + 512) = v_h;      // row k8l*5+4
}

// ------------------------------------------------------------ projection ---
// Block = 512 threads (8 waves): 128 rows x ONE 16-col group, K in 2 halves.
// Per half: stage the 80KB W slice into LDS (10x global_load_lds dwordx4
// per thread, one barrier) -- all 8 waves share it (W L2 traffic /8, and
// the DMA engine eats the global latency that killed R2-R4's reg staging).
// Main loop: per 32-K step, 2 x-loads (depth-4 rotation + SB0), 5 conflict-
// free ds_read_b128 (frag read = 4 dense 256B rows), 7 MFMA.
// Grid 512: rg=bid&127, cg=bid>>7 -> same-x blocks share an XCD L2.
__global__ __launch_bounds__(512, 4) void proj_kernel(
    const float* __restrict__ x, const __bf16* __restrict__ WC,
    __bf16* __restrict__ qh, __bf16* __restrict__ ql,
    __bf16* __restrict__ kh, __bf16* __restrict__ kl,
    __bf16* __restrict__ vt) {
  __shared__ __bf16 Wlds[WSLICE];  // 80 KB
  const int tid = threadIdx.x;
  const int w = tid >> 6, l = tid & 63;
  const int lr = l & 15, lg = l >> 4;
  const int rg = blockIdx.x & 127, cg = blockIdx.x >> 7;
  const int r0 = rg * 128 + w * 16;

  const float* xp = x + (size_t)(r0 + lr) * DD + lg * 8;
  // per-frag LDS base (bf16 elems): row (5*lg+m), chunk lr
  const int wb0 = (5 * lg + 0) * 128 + lr * 8;

  f32x4 aq = {0.f, 0.f, 0.f, 0.f};
  f32x4 ak = {0.f, 0.f, 0.f, 0.f};
  f32x4 av = {0.f, 0.f, 0.f, 0.f};
  float4 xa[4], xb[4];

#define LDX(J, OFF)                               \
  do {                                            \
    xa[J] = *(const float4*)(xp + (OFF));         \
    xb[J] = *(const float4*)(xp + (OFF) + 4);     \
  } while (0)

#define CMPW(J, S)                                                    \
  do {                                                                \
    const __bf16* fp = &Wlds[(S) * 2560 + wb0];                       \
    bf16x8 f0 = *(const bf16x8*)(fp);                                 \
    bf16x8 f1 = *(const bf16x8*)(fp + 128);                           \
    bf16x8 f2 = *(const bf16x8*)(fp + 256);                           \
    bf16x8 f3 = *(const bf16x8*)(fp + 384);                           \
    bf16x8 f4 = *(const bf16x8*)(fp + 512);                           \
    float xs[8] = {xa[J].x, xa[J].y, xa[J].z, xa[J].w,                \
                   xb[J].x, xb[J].y, xb[J].z, xb[J].w};               \
    bf16x8 ah, al;                                                    \
    _Pragma("unroll") for (int j = 0; j < 8; ++j) {                   \
      __bf16 hv = (__bf16)xs[j];                                      \
      ah[j] = hv;                                                     \
      al[j] = (__bf16)(xs[j] - (float)hv);                            \
    }                                                                 \
    aq = MFMA16(ah, f0, aq);                                          \
    aq = MFMA16(ah, f1, aq);                                          \
    aq = MFMA16(al, f0, aq);                                          \
    ak = MFMA16(ah, f2, ak);                                          \
    ak = MFMA16(ah, f3, ak);                                          \
    ak = MFMA16(al, f2, ak);                                          \
    av = MFMA16(ah, f4, av);                                          \
  } while (0)

#pragma unroll 1
  for (int h = 0; h < 2; ++h) {
    if (h) __syncthreads();  // all waves done reading half-0 W
    {
      const __bf16* wsrc = WC + (size_t)(cg * 2 + h) * WSLICE;
      const __bf16* gp = wsrc + (size_t)tid * 8;  // per-lane 16B cell
#pragma unroll
      for (int i2 = 0; i2 < 10; ++i2) {
        __builtin_amdgcn_global_load_lds(
            (const __attribute__((address_space(1))) unsigned int*)(gp + i2 * 4096),
            (__attribute__((address_space(3))) unsigned int*)
                ((char*)Wlds + w * 1024 + i2 * 8192),
            16, 0, 0);
      }
    }
    __syncthreads();  // compiler drains vmcnt before barrier: DMA complete

    const int xoff = h * 512;
    LDX(0, xoff); LDX(1, xoff + 32); LDX(2, xoff + 64); LDX(3, xoff + 96);
    SB0();
#pragma unroll
    for (int s = 0; s < 16; ++s) {
      CMPW(s & 3, s);
      if (s < 12) LDX(s & 3, xoff + (s + 4) * 32);
      SB0();
    }
  }
#undef LDX
#undef CMPW

#pragma unroll
  for (int i = 0; i < 4; ++i) {
    const int row = r0 + lg * 4 + i;  // C-layout: row=(lane>>4)*4+reg
    const int col = cg * 16 + lr;     //           col=lane&15
    const size_t oq = (size_t)row * 64 + col;
    float qv = aq[i];
    __bf16 qhi = (__bf16)qv;
    qh[oq] = qhi;
    ql[oq] = (__bf16)(qv - (float)qhi);
    float kv = ak[i];
    __bf16 khi = (__bf16)kv;
    kh[oq] = khi;
    kl[oq] = (__bf16)(kv - (float)khi);
    const int bb = row >> 11, tt = row & 2047;
    vt[((size_t)bb * 64 + col) * 2048 + tt] = (__bf16)av[i];
  }
}

// -------------------------------------------------------------- attention ---
// Split-K flash, 8-way: one block (8 waves, 512 thr) per 16-row q-tile.
// R6 post-mortem: 46.6KB LDS -> 3 blocks/CU -> only 768/1024 blocks
// resident -> batch->XCD mapping broke for the backfilled 256 -> L2
// thrash (FETCH 5MB -> 165MB). Fix: TWO-STAGE merge (OB4[4] instead of
// OB[8]) cuts LDS to 28.7KB; __launch_bounds__(512,8) caps VGPR at 64 ->
// 4 blocks/CU = all 1024 resident from t=0 (restores L2-resident K/V)
// at 32 waves/CU.
__global__ __launch_bounds__(512, 8) void attn_kernel(
    const __bf16* __restrict__ qh, const __bf16* __restrict__ ql,
    const __bf16* __restrict__ kh, const __bf16* __restrict__ kl,
    const __bf16* __restrict__ vt, float* __restrict__ out) {
  __shared__ __bf16 P[8][16][40];   // 40-col pad: 80B rows -> conflict-free b128
  __shared__ float Sm[8][16];       // per-wave row maxes
  __shared__ float Sl[8][16];       // per-wave row sums
  __shared__ float OB4[4][16][68];  // two-stage merge buffer (68 pad: <=2-way)
  __shared__ float Dinv[16];        // 1/denom per row
  const int w = threadIdx.x >> 6, l = threadIdx.x & 63;
  const int lr = l & 15, lg = l >> 4;
  const int b = blockIdx.x & 7;            // XCD affinity: batch -> XCD
  const int qt = 127 - (blockIdx.x >> 3);  // heavy tiles first
  const int q0 = qt * 16;
  const float NEG = -__builtin_inff();

  const size_t qb = ((size_t)b * TT + q0 + lr) * 64 + lg * 8;
  const bf16x8 fqh0 = *(const bf16x8*)(qh + qb);
  const bf16x8 fqh1 = *(const bf16x8*)(qh + qb + 32);
  const bf16x8 fql0 = *(const bf16x8*)(ql + qb);
  const bf16x8 fql1 = *(const bf16x8*)(ql + qb + 32);

  f32x4 o0 = {0.f, 0.f, 0.f, 0.f}, o1 = o0, o2 = o0, o3 = o0;
  float m[4] = {NEG, NEG, NEG, NEG};
  float su[4] = {0.f, 0.f, 0.f, 0.f};
  const int nkt = (q0 + 47) >> 5;  // ceil((q0+16)/32)

#pragma unroll 1
  for (int kt = w; kt < nkt; kt += 8) {
    const int j0 = kt * 32;
    const f32x4 z = {0.f, 0.f, 0.f, 0.f};
    // ---- all loads up front (KB unconditional: in-bounds, masked later) ----
    const size_t kbA = ((size_t)b * TT + j0 + lr) * 64 + lg * 8;
    const size_t kbB = kbA + (size_t)16 * 64;
    const size_t vb = ((size_t)b * 64 + lr) * 2048 + j0 + lg * 8;
    const bf16x8 fk0 = *(const bf16x8*)(kh + kbA);
    const bf16x8 fk1 = *(const bf16x8*)(kh + kbA + 32);
    const bf16x8 fl0 = *(const bf16x8*)(kl + kbA);
    const bf16x8 fl1 = *(const bf16x8*)(kl + kbA + 32);
    const bf16x8 gk0 = *(const bf16x8*)(kh + kbB);
    const bf16x8 gk1 = *(const bf16x8*)(kh + kbB + 32);
    const bf16x8 gl0 = *(const bf16x8*)(kl + kbB);
    const bf16x8 gl1 = *(const bf16x8*)(kl + kbB + 32);
    const bf16x8 v0 = *(const bf16x8*)(vt + vb);
    const bf16x8 v1 = *(const bf16x8*)(vt + vb + (size_t)16 * 2048);
    const bf16x8 v2 = *(const bf16x8*)(vt + vb + (size_t)32 * 2048);
    const bf16x8 v3 = *(const bf16x8*)(vt + vb + (size_t)48 * 2048);
    SB0();  // loads may not sink past this point

    f32x4 sa, sb = {NEG, NEG, NEG, NEG};
    {
      f32x4 c0 = MFMA16(fqh1, fk1, MFMA16(fqh0, fk0, z));
      f32x4 c1 = MFMA16(fqh1, fl1, MFMA16(fqh0, fl0, z));
      f32x4 c2 = MFMA16(fql1, fk1, MFMA16(fql0, fk0, z));
      sa = c0 + c1 + c2;
    }
    const bool haveB = (j0 + 16) <= (q0 + 15);
    if (haveB) {
      f32x4 c0 = MFMA16(fqh1, gk1, MFMA16(fqh0, gk0, z));
      f32x4 c1 = MFMA16(fqh1, gl1, MFMA16(fqh0, gl0, z));
      f32x4 c2 = MFMA16(fql1, gk1, MFMA16(fql0, gk0, z));
      sb = c0 + c1 + c2;
    }
    // causal mask (row = q0 + lg*4 + i, key = j0 [+16] + lr)
#pragma unroll
    for (int i = 0; i < 4; ++i) {
      const int rowg = q0 + lg * 4 + i;
      if (j0 + lr > rowg) sa[i] = NEG;
      if (j0 + 16 + lr > rowg) sb[i] = NEG;
    }
    // online softmax update + stage P in LDS
#pragma unroll
    for (int i = 0; i < 4; ++i) {
      float t = rmax16(fmaxf(sa[i], sb[i]));
      const float mn = fmaxf(m[i], t);
      const float sc = __expf(m[i] - mn);
      m[i] = mn;
      const float pa = __expf(sa[i] - mn);
      const float pb = __expf(sb[i] - mn);
      su[i] = su[i] * sc + rsum16(pa + pb);
      o0[i] *= sc; o1[i] *= sc; o2[i] *= sc; o3[i] *= sc;
      P[w][lg * 4 + i][lr] = (__bf16)pa;
      P[w][lg * 4 + i][16 + lr] = (__bf16)pb;
    }
    // PV: A-frag of P (same-wave LDS ops are in-order; compiler adds waits)
    const bf16x8 pf = *(const bf16x8*)(&P[w][lr][lg * 8]);
    o0 = MFMA16(pf, v0, o0);
    o1 = MFMA16(pf, v1, o1);
    o2 = MFMA16(pf, v2, o2);
    o3 = MFMA16(pf, v3, o3);
  }

  // ------- two-stage LSE merge of the 8 per-wave partials -------
  if (lr == 0) {
#pragma unroll
    for (int i = 0; i < 4; ++i) {
      Sm[w][lg * 4 + i] = m[i];
      Sl[w][lg * 4 + i] = su[i];
    }
  }
  __syncthreads();
  // global row max + scale own O; wave 0 computes Dinv
#pragma unroll
  for (int i = 0; i < 4; ++i) {
    const int row = lg * 4 + i;
    float M = NEG;
#pragma unroll
    for (int w2 = 0; w2 < 8; ++w2) M = fmaxf(M, Sm[w2][row]);
    const float sc = __expf(m[i] - M);  // 0 if this wave was idle (m=-inf)
    o0[i] *= sc; o1[i] *= sc; o2[i] *= sc; o3[i] *= sc;
    if (w == 0 && lr == 0) {
      float denom = 0.f;
#pragma unroll
      for (int w2 = 0; w2 < 8; ++w2)
        denom += Sl[w2][row] * __expf(Sm[w2][row] - M);
      Dinv[row] = 1.0f / denom;
    }
  }
  // stage 1: waves 4..7 deposit scaled O
  if (w >= 4) {
#pragma unroll
    for (int i = 0; i < 4; ++i) {
      const int row = lg * 4 + i;
      OB4[w - 4][row][lr] = o0[i];
      OB4[w - 4][row][16 + lr] = o1[i];
      OB4[w - 4][row][32 + lr] = o2[i];
      OB4[w - 4][row][48 + lr] = o3[i];
    }
  }
  __syncthreads();
  // stage 2: waves 0..3 add partner's deposit, write back to same slot
  if (w < 4) {
#pragma unroll
    for (int i = 0; i < 4; ++i) {
      const int row = lg * 4 + i;
      OB4[w][row][lr] = o0[i] + OB4[w][row][lr];
      OB4[w][row][16 + lr] = o1[i] + OB4[w][row][16 + lr];
      OB4[w][row][32 + lr] = o2[i] + OB4[w][row][32 + lr];
      OB4[w][row][48 + lr] = o3[i] + OB4[w][row][48 + lr];
    }
  }
  __syncthreads();
  // final: sum 4 slots, normalize, store (1024 elems, 512 threads)
  const int t = threadIdx.x;
#pragma unroll
  for (int k2 = 0; k2 < 2; ++k2) {
    const int e = t + 512 * k2;
    const int row = e >> 6, col = e & 63;
    const float s = OB4[0][row][col] + OB4[1][row][col] + OB4[2][row][col] +
                    OB4[3][row][col];
    out[((size_t)b * TT + q0 + row) * 64 + col] = s * Dinv[row];
  }
}

// ------------------------------------------------------------------ launch ---
extern "C" void kernel_launch(void* const* d_in, const int* in_sizes, int n_in,
                              void* d_out, int out_size, void* d_ws,
                              size_t ws_size, hipStream_t stream) {
  const float* x = (const float*)d_in[0];
  const float* Wq = (const float*)d_in[1];
  const float* Wk = (const float*)d_in[2];
  const float* Wv = (const float*)d_in[3];
  float* out = (float*)d_out;
  char* ws = (char*)d_ws;

  size_t off = 0;
  __bf16* WC = (__bf16*)(ws + off); off += (size_t)8 * WSLICE * 2;  // 655KB
  __bf16* qh = (__bf16*)(ws + off); off += (size_t)NROW * 64 * 2;
  __bf16* ql = (__bf16*)(ws + off); off += (size_t)NROW * 64 * 2;
  __bf16* kh = (__bf16*)(ws + off); off += (size_t)NROW * 64 * 2;
  __bf16* kl = (__bf16*)(ws + off); off += (size_t)NROW * 64 * 2;
  __bf16* vt = (__bf16*)(ws + off); off += (size_t)NROW * 64 * 2;  // ~11.1 MB

  wprep_kernel<<<dim3(32), dim3(256), 0, stream>>>(Wq, Wk, Wv, WC);
  proj_kernel<<<dim3(512), dim3(512), 0, stream>>>(
      x, WC, qh, ql, kh, kl, vt);
  attn_kernel<<<dim3(1024), dim3(512), 0, stream>>>(
      qh, ql, kh, kl, vt, out);
}

// Round 8
// 106.164 us; speedup vs baseline: 1.8028x; 1.8028x over previous
//
#include <hip/hip_runtime.h>
#include <hip/hip_bf16.h>

// MaskedAttention: out = softmax(tril(q k^T)) v, q/k/v = x @ W{q,k,v}
// B=8 T=2048 D=1024 H=64, fp32 in/out, no 1/sqrt(H) scaling.
//
// Precision plan: q,k projections and QK^T use hi/lo bf16 splitting
// (3-MFMA "bf16x3") so logits are ~fp32-accurate; V/P plain bf16.

typedef __bf16 bf16x8 __attribute__((ext_vector_type(8)));
typedef float f32x4 __attribute__((ext_vector_type(4)));

#define MFMA16(a, b, c) __builtin_amdgcn_mfma_f32_16x16x32_bf16((a), (b), (c), 0, 0, 0)
#define SB0() __builtin_amdgcn_sched_barrier(0)

static constexpr int BB = 8;
static constexpr int TT = 2048;
static constexpr int DD = 1024;
static constexpr int HH = 64;
static constexpr int NROW = BB * TT;       // 16384
// WC slab: [4 colgroups][2 K-halves][320 rows = k8l*5+frag][16 cols][8 bf16]
// frag: 0=q_hi 1=q_lo 2=k_hi 3=k_lo 4=v_hi. 80KB per (cg,half) slice.
static constexpr int WSLICE = 320 * 128;   // bf16 elems per (cg,half) = 80KB

// pack two floats to one u32 of 2 bf16 (lo, hi)
__device__ __forceinline__ unsigned pk2(float a, float b) {
  union { __bf16 h[2]; unsigned u; } r;
  r.h[0] = (__bf16)a;
  r.h[1] = (__bf16)b;
  return r.u;
}

// ---------------------------------------------------------------- W prep ---
// W [1024][64] fp32 -> WC slab (see above). Linear in (row,col) so proj can
// stage it to LDS with pure linear global_load_lds DMA.
__global__ __launch_bounds__(256) void wprep_kernel(
    const float* __restrict__ Wq, const float* __restrict__ Wk,
    const float* __restrict__ Wv, __bf16* __restrict__ WC) {
  int tid = blockIdx.x * 256 + threadIdx.x;
  if (tid >= 64 * 128) return;
  int col = tid >> 7;
  int k8 = tid & 127;
  const int g = col >> 4, c = col & 15;
  const int h2 = k8 >> 6, k8l = k8 & 63;
  bf16x8 q_h, q_l, k_h, k_l, v_h;
#pragma unroll
  for (int j = 0; j < 8; ++j) {
    const int k = k8 * 8 + j;
    float qv = Wq[k * 64 + col];
    float kv = Wk[k * 64 + col];
    float vv = Wv[k * 64 + col];
    __bf16 qhi = (__bf16)qv;
    __bf16 khi = (__bf16)kv;
    q_h[j] = qhi;
    q_l[j] = (__bf16)(qv - (float)qhi);
    k_h[j] = khi;
    k_l[j] = (__bf16)(kv - (float)khi);
    v_h[j] = (__bf16)vv;
  }
  __bf16* base = WC + (size_t)(g * 2 + h2) * WSLICE + (size_t)(k8l * 5) * 128 + c * 8;
  *(bf16x8*)(base) = q_h;            // row k8l*5+0
  *(bf16x8*)(base + 128) = q_l;      // row k8l*5+1
  *(bf16x8*)(base + 256) = k_h;      // row k8l*5+2
  *(bf16x8*)(base + 384) = k_l;      // row k8l*5+3
  *(bf16x8*)(base + 512) = v_h;      // row k8l*5+4
}

// ------------------------------------------------------------ projection ---
// Block = 512 threads (8 waves): 128 rows x ONE 16-col group, K in 2 halves.
// Per half: stage the 80KB W slice into LDS (10x global_load_lds dwordx4
// per thread, one barrier) -- all 8 waves share it (W L2 traffic /8, and
// the DMA engine eats the global latency that killed R2-R4's reg staging).
// Main loop: per 32-K step, 2 x-loads (depth-4 rotation + SB0), 5 conflict-
// free ds_read_b128 (frag read = 4 dense 256B rows), 7 MFMA.
// Grid 512: rg=bid&127, cg=bid>>7 -> same-x blocks share an XCD L2.
__global__ __launch_bounds__(512, 4) void proj_kernel(
    const float* __restrict__ x, const __bf16* __restrict__ WC,
    __bf16* __restrict__ qh, __bf16* __restrict__ ql,
    __bf16* __restrict__ kh, __bf16* __restrict__ kl,
    __bf16* __restrict__ vt) {
  __shared__ __bf16 Wlds[WSLICE];  // 80 KB
  const int tid = threadIdx.x;
  const int w = tid >> 6, l = tid & 63;
  const int lr = l & 15, lg = l >> 4;
  const int rg = blockIdx.x & 127, cg = blockIdx.x >> 7;
  const int r0 = rg * 128 + w * 16;

  const float* xp = x + (size_t)(r0 + lr) * DD + lg * 8;
  // per-frag LDS base (bf16 elems): row (5*lg+m), chunk lr
  const int wb0 = (5 * lg + 0) * 128 + lr * 8;

  f32x4 aq = {0.f, 0.f, 0.f, 0.f};
  f32x4 ak = {0.f, 0.f, 0.f, 0.f};
  f32x4 av = {0.f, 0.f, 0.f, 0.f};
  float4 xa[4], xb[4];

#define LDX(J, OFF)                               \
  do {                                            \
    xa[J] = *(const float4*)(xp + (OFF));         \
    xb[J] = *(const float4*)(xp + (OFF) + 4);     \
  } while (0)

#define CMPW(J, S)                                                    \
  do {                                                                \
    const __bf16* fp = &Wlds[(S) * 2560 + wb0];                       \
    bf16x8 f0 = *(const bf16x8*)(fp);                                 \
    bf16x8 f1 = *(const bf16x8*)(fp + 128);                           \
    bf16x8 f2 = *(const bf16x8*)(fp + 256);                           \
    bf16x8 f3 = *(const bf16x8*)(fp + 384);                           \
    bf16x8 f4 = *(const bf16x8*)(fp + 512);                           \
    float xs[8] = {xa[J].x, xa[J].y, xa[J].z, xa[J].w,                \
                   xb[J].x, xb[J].y, xb[J].z, xb[J].w};               \
    bf16x8 ah, al;                                                    \
    _Pragma("unroll") for (int j = 0; j < 8; ++j) {                   \
      __bf16 hv = (__bf16)xs[j];                                      \
      ah[j] = hv;                                                     \
      al[j] = (__bf16)(xs[j] - (float)hv);                            \
    }                                                                 \
    aq = MFMA16(ah, f0, aq);                                          \
    aq = MFMA16(ah, f1, aq);                                          \
    aq = MFMA16(al, f0, aq);                                          \
    ak = MFMA16(ah, f2, ak);                                          \
    ak = MFMA16(ah, f3, ak);                                          \
    ak = MFMA16(al, f2, ak);                                          \
    av = MFMA16(ah, f4, av);                                          \
  } while (0)

#pragma unroll 1
  for (int h = 0; h < 2; ++h) {
    if (h) __syncthreads();  // all waves done reading half-0 W
    {
      const __bf16* wsrc = WC + (size_t)(cg * 2 + h) * WSLICE;
      const __bf16* gp = wsrc + (size_t)tid * 8;  // per-lane 16B cell
#pragma unroll
      for (int i2 = 0; i2 < 10; ++i2) {
        __builtin_amdgcn_global_load_lds(
            (const __attribute__((address_space(1))) unsigned int*)(gp + i2 * 4096),
            (__attribute__((address_space(3))) unsigned int*)
                ((char*)Wlds + w * 1024 + i2 * 8192),
            16, 0, 0);
      }
    }
    __syncthreads();  // compiler drains vmcnt before barrier: DMA complete

    const int xoff = h * 512;
    LDX(0, xoff); LDX(1, xoff + 32); LDX(2, xoff + 64); LDX(3, xoff + 96);
    SB0();
#pragma unroll
    for (int s = 0; s < 16; ++s) {
      CMPW(s & 3, s);
      if (s < 12) LDX(s & 3, xoff + (s + 4) * 32);
      SB0();
    }
  }
#undef LDX
#undef CMPW

#pragma unroll
  for (int i = 0; i < 4; ++i) {
    const int row = r0 + lg * 4 + i;  // C-layout: row=(lane>>4)*4+reg
    const int col = cg * 16 + lr;     //           col=lane&15
    const size_t oq = (size_t)row * 64 + col;
    float qv = aq[i];
    __bf16 qhi = (__bf16)qv;
    qh[oq] = qhi;
    ql[oq] = (__bf16)(qv - (float)qhi);
    float kv = ak[i];
    __bf16 khi = (__bf16)kv;
    kh[oq] = khi;
    kl[oq] = (__bf16)(kv - (float)khi);
    const int bb = row >> 11, tt = row & 2047;
    vt[((size_t)bb * 64 + col) * 2048 + tt] = (__bf16)av[i];
  }
}

// -------------------------------------------------------------- attention ---
// Split-K flash, R5 structure (4-wave/256-thr blocks, 1024 blocks, all
// resident, batch->XCD L2 affinity) + SWAPPED QK^T in-register softmax.
// R6/R7 post-mortems: 8-wave blocks broke residency (L2 thrash) or VGPR
// budget (spill). Back to the proven config; attack the serial chain:
// mfma(K,Q) (same loads, swapped operands) puts a full q-row per lane ->
// row-max = 7 in-lane fmax + 2 shuffles (was 4x4-deep), row-sum = in-lane
// (was 4x4-deep), P->A-frag = 6-shuffle register block-transpose, no LDS
// P buffer. ~12 shuffles/iter vs 32 + LDS round-trip.
__global__ __launch_bounds__(256, 4) void attn_kernel(
    const __bf16* __restrict__ qh, const __bf16* __restrict__ ql,
    const __bf16* __restrict__ kh, const __bf16* __restrict__ kl,
    const __bf16* __restrict__ vt, float* __restrict__ out) {
  __shared__ float Sm[4][16];       // per-wave row maxes
  __shared__ float Sl[4][16];       // per-wave row sums
  __shared__ float OB[4][16][68];   // per-wave scaled O (68 pad: <=2-way, free)
  __shared__ float Dinv[16];        // 1/denom per row
  const int w = threadIdx.x >> 6, l = threadIdx.x & 63;
  const int lr = l & 15, lg = l >> 4;
  const int b = blockIdx.x & 7;            // XCD affinity: batch -> XCD
  const int qt = 127 - (blockIdx.x >> 3);  // heavy tiles first
  const int q0 = qt * 16;
  const float NEG = -__builtin_inff();

  // Q fragments (now the B-operand; same loads as before)
  const size_t qb = ((size_t)b * TT + q0 + lr) * 64 + lg * 8;
  const bf16x8 fqh0 = *(const bf16x8*)(qh + qb);
  const bf16x8 fqh1 = *(const bf16x8*)(qh + qb + 32);
  const bf16x8 fql0 = *(const bf16x8*)(ql + qb);
  const bf16x8 fql1 = *(const bf16x8*)(ql + qb + 32);

  f32x4 o0 = {0.f, 0.f, 0.f, 0.f}, o1 = o0, o2 = o0, o3 = o0;
  float m_s = NEG;   // running max for q-row (q0+lr), shared by 4 lg-lanes
  float su_s = 0.f;  // partial denom for q-row (this lane's keys only)
  const int nkt = (q0 + 47) >> 5;  // ceil((q0+16)/32)

#pragma unroll 1
  for (int kt = w; kt < nkt; kt += 4) {
    const int j0 = kt * 32;
    const f32x4 z = {0.f, 0.f, 0.f, 0.f};
    // ---- all loads up front (KB unconditional: in-bounds, masked later) ----
    const size_t kbA = ((size_t)b * TT + j0 + lr) * 64 + lg * 8;
    const size_t kbB = kbA + (size_t)16 * 64;
    const size_t vb = ((size_t)b * 64 + lr) * 2048 + j0 + lg * 8;
    const bf16x8 fk0 = *(const bf16x8*)(kh + kbA);
    const bf16x8 fk1 = *(const bf16x8*)(kh + kbA + 32);
    const bf16x8 fl0 = *(const bf16x8*)(kl + kbA);
    const bf16x8 fl1 = *(const bf16x8*)(kl + kbA + 32);
    const bf16x8 gk0 = *(const bf16x8*)(kh + kbB);
    const bf16x8 gk1 = *(const bf16x8*)(kh + kbB + 32);
    const bf16x8 gl0 = *(const bf16x8*)(kl + kbB);
    const bf16x8 gl1 = *(const bf16x8*)(kl + kbB + 32);
    const bf16x8 v0 = *(const bf16x8*)(vt + vb);
    const bf16x8 v1 = *(const bf16x8*)(vt + vb + (size_t)16 * 2048);
    const bf16x8 v2 = *(const bf16x8*)(vt + vb + (size_t)32 * 2048);
    const bf16x8 v3 = *(const bf16x8*)(vt + vb + (size_t)48 * 2048);
    SB0();  // loads may not sink past this point

    // swapped QK^T: S^T[key][q].  sa: keys j0+lg*4+i, q=q0+lr.
    f32x4 sa, sb = {NEG, NEG, NEG, NEG};
    {
      f32x4 c0 = MFMA16(fk1, fqh1, MFMA16(fk0, fqh0, z));
      f32x4 c1 = MFMA16(fk1, fql1, MFMA16(fk0, fql0, z));
      f32x4 c2 = MFMA16(fl1, fqh1, MFMA16(fl0, fqh0, z));
      sa = c0 + c1 + c2;
    }
    const bool haveB = (j0 + 16) <= (q0 + 15);
    if (haveB) {
      f32x4 c0 = MFMA16(gk1, fqh1, MFMA16(gk0, fqh0, z));
      f32x4 c1 = MFMA16(gk1, fql1, MFMA16(gk0, fql0, z));
      f32x4 c2 = MFMA16(gl1, fqh1, MFMA16(gl0, fqh0, z));
      sb = c0 + c1 + c2;
    }
    // causal mask: key = j0 (+16) + lg*4+i, q = q0 + lr
#pragma unroll
    for (int i = 0; i < 4; ++i) {
      if (j0 + lg * 4 + i > q0 + lr) sa[i] = NEG;
      if (j0 + 16 + lg * 4 + i > q0 + lr) sb[i] = NEG;
    }
    // in-register online softmax for q-row lr (4 lg-lanes cooperate)
    float t = fmaxf(fmaxf(fmaxf(sa[0], sa[1]), fmaxf(sa[2], sa[3])),
                    fmaxf(fmaxf(sb[0], sb[1]), fmaxf(sb[2], sb[3])));
    t = fmaxf(t, __shfl_xor(t, 16, 64));
    t = fmaxf(t, __shfl_xor(t, 32, 64));
    const float mn = fmaxf(m_s, t);
    const float sc = __expf(m_s - mn);
    m_s = mn;
    const float pa0 = __expf(sa[0] - mn), pa1 = __expf(sa[1] - mn);
    const float pa2 = __expf(sa[2] - mn), pa3 = __expf(sa[3] - mn);
    const float pb0 = __expf(sb[0] - mn), pb1 = __expf(sb[1] - mn);
    const float pb2 = __expf(sb[2] - mn), pb3 = __expf(sb[3] - mn);
    su_s = su_s * sc + ((pa0 + pa1) + (pa2 + pa3)) +
           ((pb0 + pb1) + (pb2 + pb3));
    // per-output-row rescale (output row = q0+lg*4+i; its sc lives at lane
    // lg*4+i, which has lr==lg*4+i)
#pragma unroll
    for (int i = 0; i < 4; ++i) {
      const float scr = __shfl(sc, lg * 4 + i, 64);
      o0[i] *= scr; o1[i] *= scr; o2[i] *= scr; o3[i] *= scr;
    }
    // pack P to bf16 pairs and block-transpose to the PV A-fragment:
    // target lane lg needs keys lg*8..lg*8+7 of q-row lr.
    const unsigned x0 = pk2(pa0, pa1), x1 = pk2(pa2, pa3);
    const unsigned y0 = pk2(pb0, pb1), y1 = pk2(pb2, pb3);
    const bool e = (lg & 1) != 0;
    const unsigned s0 = e ? x0 : y0, s1 = e ? x1 : y1;
    const unsigned r0 = __shfl_xor(s0, 16, 64);
    const unsigned r1 = __shfl_xor(s1, 16, 64);
    unsigned z0 = e ? r0 : x0;
    unsigned z1 = e ? r1 : x1;
    unsigned z2 = e ? y0 : r0;
    unsigned z3 = e ? y1 : r1;
    const unsigned u0 = __shfl_xor(z0, 48, 64);
    const unsigned u1 = __shfl_xor(z1, 48, 64);
    const unsigned u2 = __shfl_xor(z2, 48, 64);
    const unsigned u3 = __shfl_xor(z3, 48, 64);
    const bool sw = (lg == 1) || (lg == 2);
    z0 = sw ? u0 : z0; z1 = sw ? u1 : z1;
    z2 = sw ? u2 : z2; z3 = sw ? u3 : z3;
    union { unsigned u[4]; bf16x8 v; } pfu;
    pfu.u[0] = z0; pfu.u[1] = z1; pfu.u[2] = z2; pfu.u[3] = z3;
    const bf16x8 pf = pfu.v;
    // PV (pf straight from registers; no LDS round-trip)
    o0 = MFMA16(pf, v0, o0);
    o1 = MFMA16(pf, v1, o1);
    o2 = MFMA16(pf, v2, o2);
    o3 = MFMA16(pf, v3, o3);
  }

  // per-output-row final running max; full row denom (sum over 4 lg-lanes)
  float m_or[4];
#pragma unroll
  for (int i = 0; i < 4; ++i) m_or[i] = __shfl(m_s, lg * 4 + i, 64);
  float su_row = su_s;
  su_row += __shfl_xor(su_row, 16, 64);
  su_row += __shfl_xor(su_row, 32, 64);

  // ------- LSE merge of the 4 per-wave partials -------
  if (l < 16) {  // lg==0 lanes cover lr=0..15
    Sm[w][l] = m_s;
    Sl[w][l] = su_row;
  }
  __syncthreads();
#pragma unroll
  for (int i = 0; i < 4; ++i) {
    const int row = lg * 4 + i;
    float M = fmaxf(fmaxf(Sm[0][row], Sm[1][row]),
                    fmaxf(Sm[2][row], Sm[3][row]));
    const float sc = __expf(m_or[i] - M);  // 0 if this wave was idle
    OB[w][row][lr] = o0[i] * sc;
    OB[w][row][16 + lr] = o1[i] * sc;
    OB[w][row][32 + lr] = o2[i] * sc;
    OB[w][row][48 + lr] = o3[i] * sc;
    if (w == 0 && lr == 0) {
      float denom = 0.f;
#pragma unroll
      for (int w2 = 0; w2 < 4; ++w2)
        denom += Sl[w2][row] * __expf(Sm[w2][row] - M);
      Dinv[row] = 1.0f / denom;
    }
  }
  __syncthreads();
  const int t2 = threadIdx.x;
#pragma unroll
  for (int k2 = 0; k2 < 4; ++k2) {
    const int e2 = t2 + 256 * k2;
    const int row = e2 >> 6, col = e2 & 63;
    const float s = OB[0][row][col] + OB[1][row][col] + OB[2][row][col] +
                    OB[3][row][col];
    out[((size_t)b * TT + q0 + row) * 64 + col] = s * Dinv[row];
  }
}

// ------------------------------------------------------------------ launch ---
extern "C" void kernel_launch(void* const* d_in, const int* in_sizes, int n_in,
                              void* d_out, int out_size, void* d_ws,
                              size_t ws_size, hipStream_t stream) {
  const float* x = (const float*)d_in[0];
  const float* Wq = (const float*)d_in[1];
  const float* Wk = (const float*)d_in[2];
  const float* Wv = (const float*)d_in[3];
  float* out = (float*)d_out;
  char* ws = (char*)d_ws;

  size_t off = 0;
  __bf16* WC = (__bf16*)(ws + off); off += (size_t)8 * WSLICE * 2;  // 655KB
  __bf16* qh = (__bf16*)(ws + off); off += (size_t)NROW * 64 * 2;
  __bf16* ql = (__bf16*)(ws + off); off += (size_t)NROW * 64 * 2;
  __bf16* kh = (__bf16*)(ws + off); off += (size_t)NROW * 64 * 2;
  __bf16* kl = (__bf16*)(ws + off); off += (size_t)NROW * 64 * 2;
  __bf16* vt = (__bf16*)(ws + off); off += (size_t)NROW * 64 * 2;  // ~11.1 MB

  wprep_kernel<<<dim3(32), dim3(256), 0, stream>>>(Wq, Wk, Wv, WC);
  proj_kernel<<<dim3(512), dim3(512), 0, stream>>>(
      x, WC, qh, ql, kh, kl, vt);
  attn_kernel<<<dim3(1024), dim3(256), 0, stream>>>(
      qh, ql, kh, kl, vt, out);
}